// Round 1
// baseline (1247.642 us; speedup 1.0000x reference)
//
#include <hip/hip_runtime.h>
#include <stdint.h>

// ---------------------------------------------------------------------------
// MultiHeadSelfAttention: x(2,2048,1024) fp32, w_qkv(1024,3072), w_out(1024,1024)
// Pipeline: cast/transpose -> bf16 MFMA GEMM (qkv) -> RoPE+reorg -> scalar
// flash attention (causal) -> bf16 MFMA GEMM (out proj, fp32 store).
// Round 0: correctness-first. Reg-staged LDS GEMM (global_load_lds next round),
// scalar attention (MFMA attention next rounds).
// ---------------------------------------------------------------------------

#define B_ 2
#define T_ 2048
#define C_ 1024
#define H_ 16
#define D_ 64
#define F_ 3072
#define M_ 4096

typedef unsigned short u16;
typedef u16 u16x4 __attribute__((ext_vector_type(4)));
typedef u16 u16x8 __attribute__((ext_vector_type(8)));
typedef __bf16 bf16x8 __attribute__((ext_vector_type(8)));
typedef float f32x4 __attribute__((ext_vector_type(4)));

__device__ __forceinline__ float b2f(u16 u) {
  union { unsigned int i; float f; } v; v.i = ((unsigned int)u) << 16; return v.f;
}
__device__ __forceinline__ u16 f2b(float f) {  // RNE, finite inputs
  unsigned int u = __float_as_uint(f);
  u += 0x7fffu + ((u >> 16) & 1u);
  return (u16)(u >> 16);
}

// --------------------------- small prep kernels ----------------------------

__global__ __launch_bounds__(256) void rope_table_kernel(float* cosT, float* sinT) {
  int idx = blockIdx.x * 256 + threadIdx.x;    // T_*32 = 65536 threads
  int t = idx >> 5, i = idx & 31;
  float inv_freq = powf(10000.0f, -(float)(2 * i) / 64.0f);
  float ang = (float)t * inv_freq;
  cosT[idx] = cosf(ang);
  sinT[idx] = sinf(ang);
}

__global__ __launch_bounds__(256) void cast_x_kernel(const float* __restrict__ x,
                                                     u16* __restrict__ xb) {
  int i = blockIdx.x * 256 + threadIdx.x;      // M_*C_/4 threads
  float4 v = ((const float4*)x)[i];
  u16x4 r;
  r[0] = f2b(v.x); r[1] = f2b(v.y); r[2] = f2b(v.z); r[3] = f2b(v.w);
  ((u16x4*)xb)[i] = r;
}

// out[c][r] = bf16(in[r][c]);  R rows, Ccol cols in input. 32x32 tiles.
__global__ __launch_bounds__(256) void transpose_cast_kernel(const float* __restrict__ in,
                                                             u16* __restrict__ out,
                                                             int R, int Ccol) {
  __shared__ float tile[32][33];
  int c0 = blockIdx.x * 32, r0 = blockIdx.y * 32;
  int tx = threadIdx.x & 31, ty = threadIdx.x >> 5;   // ty = 0..7
  #pragma unroll
  for (int i = 0; i < 32; i += 8)
    tile[ty + i][tx] = in[(size_t)(r0 + ty + i) * Ccol + c0 + tx];
  __syncthreads();
  #pragma unroll
  for (int i = 0; i < 32; i += 8)
    out[(size_t)(c0 + ty + i) * R + r0 + tx] = f2b(tile[tx][ty + i]);
}

// ------------------------------- MFMA GEMM ---------------------------------
// C[M,N] = A[M,K] * Bt[N,K]^T, all bf16 in, TO out (u16=bf16 or float).
// 128x128 tile, BK=32, 4 waves (2x2), 4x4 16x16x32 MFMA frags per wave.
template <typename TO>
__global__ __launch_bounds__(256) void gemm_bt_kernel(const u16* __restrict__ A,
                                                      const u16* __restrict__ Bt,
                                                      TO* __restrict__ Cm,
                                                      int M, int N, int K) {
  constexpr int LDA = 40;  // pad 32->40 elems (80B rows, 16B aligned, conflict-light)
  __shared__ u16 sA[128 * LDA];
  __shared__ u16 sB[128 * LDA];
  const int tid = threadIdx.x;
  const int lane = tid & 63;
  const int wv = tid >> 6;
  const int wr = wv >> 1, wc = wv & 1;
  const int l16 = lane & 15, lq = lane >> 4;
  const int rowBase = blockIdx.y * 128;
  const int colBase = blockIdx.x * 128;

  f32x4 acc[4][4] = {};

  for (int k0 = 0; k0 < K; k0 += 32) {
    // stage: 512 chunks of 8 bf16 (16B) each for A and B
    #pragma unroll
    for (int p = 0; p < 2; ++p) {
      int c = p * 256 + tid;
      int r = c >> 2, c8 = (c & 3) * 8;
      u16x8 va = *(const u16x8*)(A + (size_t)(rowBase + r) * K + k0 + c8);
      u16x8 vb = *(const u16x8*)(Bt + (size_t)(colBase + r) * K + k0 + c8);
      *(u16x8*)&sA[r * LDA + c8] = va;
      *(u16x8*)&sB[r * LDA + c8] = vb;
    }
    __syncthreads();
    bf16x8 af[4], bf[4];
    #pragma unroll
    for (int m = 0; m < 4; ++m)
      af[m] = *(const bf16x8*)&sA[(wr * 64 + m * 16 + l16) * LDA + lq * 8];
    #pragma unroll
    for (int n = 0; n < 4; ++n)
      bf[n] = *(const bf16x8*)&sB[(wc * 64 + n * 16 + l16) * LDA + lq * 8];
    #pragma unroll
    for (int m = 0; m < 4; ++m)
      #pragma unroll
      for (int n = 0; n < 4; ++n)
        acc[m][n] = __builtin_amdgcn_mfma_f32_16x16x32_bf16(af[m], bf[n], acc[m][n], 0, 0, 0);
    __syncthreads();
  }

  // C/D layout (verified m89): col = lane&15, row = (lane>>4)*4 + reg
  #pragma unroll
  for (int m = 0; m < 4; ++m) {
    #pragma unroll
    for (int n = 0; n < 4; ++n) {
      int row = rowBase + wr * 64 + m * 16 + lq * 4;
      int col = colBase + wc * 64 + n * 16 + l16;
      #pragma unroll
      for (int j = 0; j < 4; ++j) {
        float v = acc[m][n][j];
        if constexpr (sizeof(TO) == 2) {
          Cm[(size_t)(row + j) * N + col] = f2b(v);
        } else {
          Cm[(size_t)(row + j) * N + col] = v;
        }
      }
    }
  }
}

// ----------------------------- RoPE + reorg --------------------------------
// qkv[M_,F_] bf16 -> qr/kr/vr [B,H,T,D] bf16 (rope on q,k; copy v)
__global__ __launch_bounds__(256) void rope_reorg_kernel(const u16* __restrict__ qkv,
                                                         const float* __restrict__ cosT,
                                                         const float* __restrict__ sinT,
                                                         u16* __restrict__ qr,
                                                         u16* __restrict__ kr,
                                                         u16* __restrict__ vr) {
  int idx = blockIdx.x * 256 + threadIdx.x;   // B*T*H*32 = 2^21 threads
  int d2 = idx & 31;
  int h = (idx >> 5) & 15;
  int t = (idx >> 9) & 2047;
  int b = idx >> 20;
  size_t base = (size_t)(b * T_ + t) * F_ + h * 64 + d2 * 2;
  float qe = b2f(qkv[base]),        qo = b2f(qkv[base + 1]);
  float ke = b2f(qkv[base + C_]),   ko = b2f(qkv[base + C_ + 1]);
  float cv = cosT[t * 32 + d2], sv = sinT[t * 32 + d2];
  size_t ob = ((size_t)(b * H_ + h) * T_ + t) * D_ + d2 * 2;
  qr[ob]     = f2b(qe * cv - qo * sv);
  qr[ob + 1] = f2b(qe * sv + qo * cv);
  kr[ob]     = f2b(ke * cv - ko * sv);
  kr[ob + 1] = f2b(ke * sv + ko * cv);
  vr[ob]     = qkv[base + 2 * C_];
  vr[ob + 1] = qkv[base + 2 * C_ + 1];
}

// --------------------------- flash attention -------------------------------
// 1 wave/block, lane = q-row (64 rows/block). grid = (B*H, T/64), blockIdx.y
// reversed so longest blocks dispatch first. K/V tiles (64x64) staged fp32 in
// LDS; inner loop: broadcast ds_read_b128 + fp32 FMA; online softmax.
__global__ __launch_bounds__(64) void attn_kernel(const u16* __restrict__ qr,
                                                  const u16* __restrict__ kr,
                                                  const u16* __restrict__ vr,
                                                  u16* __restrict__ attn_out) {
  __shared__ float sK[64 * 64];
  __shared__ float sV[64 * 64];
  const int lane = threadIdx.x;
  const int bh = blockIdx.x;
  const int rt = (int)gridDim.y - 1 - (int)blockIdx.y;
  const int t = rt * 64 + lane;
  const size_t hb = (size_t)bh * T_ * D_;

  float q[64];
  {
    const u16x8* qp = (const u16x8*)(qr + hb + (size_t)t * D_);
    #pragma unroll
    for (int j = 0; j < 8; ++j) {
      u16x8 v = qp[j];
      #pragma unroll
      for (int u = 0; u < 8; ++u) q[j * 8 + u] = b2f(v[u]);
    }
  }
  float o[64];
  #pragma unroll
  for (int d = 0; d < 64; ++d) o[d] = 0.0f;
  float mx = -1e30f, l = 0.0f;

  const int ntiles = rt + 1;
  for (int tile = 0; tile < ntiles; ++tile) {
    const int k0 = tile * 64;
    __syncthreads();
    // stage K,V tile: 1024 chunks of 4 floats; chunk = j*64+lane
    #pragma unroll 4
    for (int j = 0; j < 16; ++j) {
      int cchunk = j * 64 + lane;
      int r = cchunk >> 4, c4 = (cchunk & 15) * 4;
      u16x4 uk = *(const u16x4*)(kr + hb + (size_t)(k0 + r) * D_ + c4);
      u16x4 uv = *(const u16x4*)(vr + hb + (size_t)(k0 + r) * D_ + c4);
      *(float4*)&sK[cchunk * 4] = make_float4(b2f(uk[0]), b2f(uk[1]), b2f(uk[2]), b2f(uk[3]));
      *(float4*)&sV[cchunk * 4] = make_float4(b2f(uv[0]), b2f(uv[1]), b2f(uv[2]), b2f(uv[3]));
    }
    __syncthreads();
    const int kmax = min(64, t - k0 + 1);
    for (int kk = 0; kk < kmax; ++kk) {
      float s0 = 0.f, s1 = 0.f, s2 = 0.f, s3 = 0.f;
      #pragma unroll
      for (int dc = 0; dc < 16; ++dc) {
        float4 kv = *(const float4*)&sK[kk * 64 + dc * 4];
        s0 = fmaf(q[dc * 4 + 0], kv.x, s0);
        s1 = fmaf(q[dc * 4 + 1], kv.y, s1);
        s2 = fmaf(q[dc * 4 + 2], kv.z, s2);
        s3 = fmaf(q[dc * 4 + 3], kv.w, s3);
      }
      float s = ((s0 + s1) + (s2 + s3)) * 0.125f;
      if (s > mx) {
        float corr = __expf(mx - s);
        l *= corr;
        #pragma unroll
        for (int d = 0; d < 64; ++d) o[d] *= corr;
        mx = s;
      }
      float p = __expf(s - mx);
      l += p;
      #pragma unroll
      for (int dc = 0; dc < 16; ++dc) {
        float4 vv = *(const float4*)&sV[kk * 64 + dc * 4];
        o[dc * 4 + 0] = fmaf(p, vv.x, o[dc * 4 + 0]);
        o[dc * 4 + 1] = fmaf(p, vv.y, o[dc * 4 + 1]);
        o[dc * 4 + 2] = fmaf(p, vv.z, o[dc * 4 + 2]);
        o[dc * 4 + 3] = fmaf(p, vv.w, o[dc * 4 + 3]);
      }
    }
  }

  const float inv = 1.0f / l;
  const int b = bh >> 4, h = bh & 15;
  u16* orow = attn_out + ((size_t)(b * T_ + t)) * C_ + h * 64;
  #pragma unroll
  for (int j = 0; j < 16; ++j) {
    u16x4 w;
    w[0] = f2b(o[j * 4 + 0] * inv);
    w[1] = f2b(o[j * 4 + 1] * inv);
    w[2] = f2b(o[j * 4 + 2] * inv);
    w[3] = f2b(o[j * 4 + 3] * inv);
    *(u16x4*)(orow + j * 4) = w;
  }
}

// ------------------------------- launcher ----------------------------------
// ws layout (bytes):                              size
//   xb     @ 0           bf16 x           8,388,608
//   wqkvT  @ 8388608     bf16 w_qkv^T     6,291,456
//   woutT  @ 14680064    bf16 w_out^T     2,097,152
//   qkv    @ 16777216    bf16 qkv        25,165,824
//   qr     @ 41943040    bf16 [B,H,T,D]   8,388,608
//   kr     @ 50331648                     8,388,608
//   vr     @ 58720256                     8,388,608
//   ao     @ 67108864    bf16 attn out    8,388,608
//   cosT   @ 75497472    f32                262,144
//   sinT   @ 75759616    f32                262,144
//   total ~76.0 MB
extern "C" void kernel_launch(void* const* d_in, const int* in_sizes, int n_in,
                              void* d_out, int out_size, void* d_ws, size_t ws_size,
                              hipStream_t stream) {
  const float* x     = (const float*)d_in[0];
  const float* w_qkv = (const float*)d_in[1];
  const float* w_out = (const float*)d_in[2];
  float* out = (float*)d_out;
  char* ws = (char*)d_ws;

  u16* xb     = (u16*)(ws + 0);
  u16* wqkvT  = (u16*)(ws + 8388608);
  u16* woutT  = (u16*)(ws + 14680064);
  u16* qkv    = (u16*)(ws + 16777216);
  u16* qr     = (u16*)(ws + 41943040);
  u16* kr     = (u16*)(ws + 50331648);
  u16* vr     = (u16*)(ws + 58720256);
  u16* ao     = (u16*)(ws + 67108864);
  float* cosT = (float*)(ws + 75497472);
  float* sinT = (float*)(ws + 75759616);

  rope_table_kernel<<<256, 256, 0, stream>>>(cosT, sinT);
  cast_x_kernel<<<4096, 256, 0, stream>>>(x, xb);
  transpose_cast_kernel<<<dim3(96, 32), 256, 0, stream>>>(w_qkv, wqkvT, C_, F_);
  transpose_cast_kernel<<<dim3(32, 32), 256, 0, stream>>>(w_out, woutT, C_, C_);
  gemm_bt_kernel<u16><<<dim3(F_ / 128, M_ / 128), 256, 0, stream>>>(xb, wqkvT, qkv, M_, F_, C_);
  rope_reorg_kernel<<<8192, 256, 0, stream>>>(qkv, cosT, sinT, qr, kr, vr);
  attn_kernel<<<dim3(B_ * H_, T_ / 64), 64, 0, stream>>>(qr, kr, vr, ao);
  gemm_bt_kernel<float><<<dim3(C_ / 128, M_ / 128), 256, 0, stream>>>(ao, woutT, out, M_, C_, C_);
}

// Round 3
// 159.807 us; speedup vs baseline: 7.8072x; 7.8072x over previous
//
#include <hip/hip_runtime.h>
#include <stdint.h>

// ---------------------------------------------------------------------------
// MultiHeadSelfAttention: x(2,2048,1024) fp32, w_qkv(1024,3072), w_out(1024,1024)
// R2: fix R1's softmax lane-space bug — O-rescale correction must be broadcast
// from l16-space (softmax state, S^T column) to D-row space (lq*4+j) before
// scaling the PV accumulator. Also: Q pre-scaled in rope_reorg (single bf16
// rounding), fully-masked-tile skip for low waves. GEMMs unchanged (R0-pass).
// ---------------------------------------------------------------------------

#define B_ 2
#define T_ 2048
#define C_ 1024
#define H_ 16
#define D_ 64
#define F_ 3072
#define M_ 4096

typedef unsigned short u16;
typedef u16 u16x2 __attribute__((ext_vector_type(2)));
typedef u16 u16x4 __attribute__((ext_vector_type(4)));
typedef u16 u16x8 __attribute__((ext_vector_type(8)));
typedef __bf16 bf16x4 __attribute__((ext_vector_type(4)));
typedef __bf16 bf16x8 __attribute__((ext_vector_type(8)));
typedef float f32x4 __attribute__((ext_vector_type(4)));

__device__ __forceinline__ float b2f(u16 u) {
  union { unsigned int i; float f; } v; v.i = ((unsigned int)u) << 16; return v.f;
}
__device__ __forceinline__ u16 f2b(float f) {  // RNE, finite inputs
  unsigned int u = __float_as_uint(f);
  u += 0x7fffu + ((u >> 16) & 1u);
  return (u16)(u >> 16);
}
__device__ __forceinline__ bf16x8 u2b8(u16x8 v) {
  union { u16x8 u; bf16x8 b; } x; x.u = v; return x.b;
}

// --------------------------- small prep kernels ----------------------------

__global__ __launch_bounds__(256) void rope_table_kernel(float* cosT, float* sinT) {
  int idx = blockIdx.x * 256 + threadIdx.x;    // T_*32 = 65536 threads
  int t = idx >> 5, i = idx & 31;
  float inv_freq = powf(10000.0f, -(float)(2 * i) / 64.0f);
  float ang = (float)t * inv_freq;
  cosT[idx] = cosf(ang);
  sinT[idx] = sinf(ang);
}

__global__ __launch_bounds__(256) void cast_x_kernel(const float* __restrict__ x,
                                                     u16* __restrict__ xb) {
  int i = blockIdx.x * 256 + threadIdx.x;      // M_*C_/4 threads
  float4 v = ((const float4*)x)[i];
  u16x4 r;
  r[0] = f2b(v.x); r[1] = f2b(v.y); r[2] = f2b(v.z); r[3] = f2b(v.w);
  ((u16x4*)xb)[i] = r;
}

// out[c][r] = bf16(in[r][c]);  R rows, Ccol cols in input. 32x32 tiles.
__global__ __launch_bounds__(256) void transpose_cast_kernel(const float* __restrict__ in,
                                                             u16* __restrict__ out,
                                                             int R, int Ccol) {
  __shared__ float tile[32][33];
  int c0 = blockIdx.x * 32, r0 = blockIdx.y * 32;
  int tx = threadIdx.x & 31, ty = threadIdx.x >> 5;   // ty = 0..7
  #pragma unroll
  for (int i = 0; i < 32; i += 8)
    tile[ty + i][tx] = in[(size_t)(r0 + ty + i) * Ccol + c0 + tx];
  __syncthreads();
  #pragma unroll
  for (int i = 0; i < 32; i += 8)
    out[(size_t)(c0 + ty + i) * R + r0 + tx] = f2b(tile[tx][ty + i]);
}

// ------------------------------- MFMA GEMM ---------------------------------
// C[M,N] = A[M,K] * Bt[N,K]^T, all bf16 in, TO out (u16=bf16 or float).
// 128x128 tile, BK=32, 4 waves (2x2), 4x4 16x16x32 MFMA frags per wave.
template <typename TO>
__global__ __launch_bounds__(256) void gemm_bt_kernel(const u16* __restrict__ A,
                                                      const u16* __restrict__ Bt,
                                                      TO* __restrict__ Cm,
                                                      int M, int N, int K) {
  constexpr int LDA = 40;  // pad 32->40 elems (80B rows, 16B aligned, conflict-light)
  __shared__ u16 sA[128 * LDA];
  __shared__ u16 sB[128 * LDA];
  const int tid = threadIdx.x;
  const int lane = tid & 63;
  const int wv = tid >> 6;
  const int wr = wv >> 1, wc = wv & 1;
  const int l16 = lane & 15, lq = lane >> 4;
  const int rowBase = blockIdx.y * 128;
  const int colBase = blockIdx.x * 128;

  f32x4 acc[4][4] = {};

  for (int k0 = 0; k0 < K; k0 += 32) {
    // stage: 512 chunks of 8 bf16 (16B) each for A and B
    #pragma unroll
    for (int p = 0; p < 2; ++p) {
      int c = p * 256 + tid;
      int r = c >> 2, c8 = (c & 3) * 8;
      u16x8 va = *(const u16x8*)(A + (size_t)(rowBase + r) * K + k0 + c8);
      u16x8 vb = *(const u16x8*)(Bt + (size_t)(colBase + r) * K + k0 + c8);
      *(u16x8*)&sA[r * LDA + c8] = va;
      *(u16x8*)&sB[r * LDA + c8] = vb;
    }
    __syncthreads();
    bf16x8 af[4], bf[4];
    #pragma unroll
    for (int m = 0; m < 4; ++m)
      af[m] = *(const bf16x8*)&sA[(wr * 64 + m * 16 + l16) * LDA + lq * 8];
    #pragma unroll
    for (int n = 0; n < 4; ++n)
      bf[n] = *(const bf16x8*)&sB[(wc * 64 + n * 16 + l16) * LDA + lq * 8];
    #pragma unroll
    for (int m = 0; m < 4; ++m)
      #pragma unroll
      for (int n = 0; n < 4; ++n)
        acc[m][n] = __builtin_amdgcn_mfma_f32_16x16x32_bf16(af[m], bf[n], acc[m][n], 0, 0, 0);
    __syncthreads();
  }

  // C/D layout (verified m89): col = lane&15, row = (lane>>4)*4 + reg
  #pragma unroll
  for (int m = 0; m < 4; ++m) {
    #pragma unroll
    for (int n = 0; n < 4; ++n) {
      int row = rowBase + wr * 64 + m * 16 + lq * 4;
      int col = colBase + wc * 64 + n * 16 + l16;
      #pragma unroll
      for (int j = 0; j < 4; ++j) {
        float v = acc[m][n][j];
        if constexpr (sizeof(TO) == 2) {
          Cm[(size_t)(row + j) * N + col] = f2b(v);
        } else {
          Cm[(size_t)(row + j) * N + col] = v;
        }
      }
    }
  }
}

// ----------------------------- RoPE + reorg --------------------------------
// qkv[M_,F_] bf16 -> qr/kr/vr [B,H,T,D] bf16 (rope on q,k; copy v)
// qr is PRE-SCALED by 0.125*log2(e) (exp2-domain softmax, single bf16 round).
__global__ __launch_bounds__(256) void rope_reorg_kernel(const u16* __restrict__ qkv,
                                                         const float* __restrict__ cosT,
                                                         const float* __restrict__ sinT,
                                                         u16* __restrict__ qr,
                                                         u16* __restrict__ kr,
                                                         u16* __restrict__ vr) {
  const float QSC = 0.125f * 1.44269504f;
  int idx = blockIdx.x * 256 + threadIdx.x;   // B*T*H*32 = 2^21 threads
  int d2 = idx & 31;
  int h = (idx >> 5) & 15;
  int t = (idx >> 9) & 2047;
  int b = idx >> 20;
  size_t base = (size_t)(b * T_ + t) * F_ + h * 64 + d2 * 2;
  float qe = b2f(qkv[base]),        qo = b2f(qkv[base + 1]);
  float ke = b2f(qkv[base + C_]),   ko = b2f(qkv[base + C_ + 1]);
  float cv = cosT[t * 32 + d2], sv = sinT[t * 32 + d2];
  size_t ob = ((size_t)(b * H_ + h) * T_ + t) * D_ + d2 * 2;
  qr[ob]     = f2b((qe * cv - qo * sv) * QSC);
  qr[ob + 1] = f2b((qe * sv + qo * cv) * QSC);
  kr[ob]     = f2b(ke * cv - ko * sv);
  kr[ob + 1] = f2b(ke * sv + ko * cv);
  vr[ob]     = qkv[base + 2 * C_];
  vr[ob + 1] = qkv[base + 2 * C_ + 1];
}

// ------------------------- MFMA flash attention ----------------------------
// Swapped QK^T (S^T = mfma(K,Q)): softmax state (mrow/lrow) lives in q=l16
// space (S^T column). PV accumulator o[][] lives in q=lq*4+j space (D-row).
// ALL cross-space transfers go through __shfl(.., lq*4+j):
//   - O-rescale correction (R1 bug: was applied without the shfl)
//   - final 1/l normalization
__global__ __launch_bounds__(256) void attn_mfma_kernel(const u16* __restrict__ qr,
                                                        const u16* __restrict__ kr,
                                                        const u16* __restrict__ vr,
                                                        u16* __restrict__ ao) {
  constexpr int LDK = 72, LDVT = 72, LDP = 72;
  __shared__ u16 sK[64 * LDK];
  __shared__ u16 sVt[64 * LDVT];                 // sVt[d][k]
  __shared__ u16 sP[4][32 * LDP];                // per-wave P[q][k]

  const int tid = threadIdx.x;
  const int lane = tid & 63;
  const int w = tid >> 6;
  const int l16 = lane & 15, lq = lane >> 4;
  const int bh = blockIdx.x;
  const int qt = (int)gridDim.y - 1 - (int)blockIdx.y;   // long blocks first
  const int qbase = qt * 128;
  const size_t hb = (size_t)bh * (T_ * D_);

  // Q frags (pre-scaled bf16, direct reinterpret)
  bf16x8 qv[2][2];
  #pragma unroll
  for (int qf = 0; qf < 2; ++qf)
    #pragma unroll
    for (int dc = 0; dc < 2; ++dc) {
      int row = qbase + w * 32 + qf * 16 + l16;
      qv[qf][dc] = u2b8(*(const u16x8*)(qr + hb + (size_t)row * 64 + dc * 32 + lq * 8));
    }

  f32x4 o[2][4] = {};                 // o[qf][dt]: O[q=lq*4+j][d=dt*16+l16]
  float mrow[2] = {-1e30f, -1e30f};   // running max (log2 domain), row q=l16
  float lrow[2] = {0.0f, 0.0f};       // per-lane partial denom, row q=l16

  const int qmaxw = qbase + w * 32 + 31;   // max q-row this wave owns
  const int nt = qt * 2 + 2;
  for (int it = 0; it < nt; ++it) {
    const int k0 = it * 64;
    __syncthreads();
    // ---- stage K[64][64] ----
    #pragma unroll
    for (int r = 0; r < 2; ++r) {
      int c = r * 256 + tid;
      int kk = c >> 3, d0 = (c & 7) * 8;
      u16x8 kv = *(const u16x8*)(kr + hb + (size_t)(k0 + kk) * 64 + d0);
      *(u16x8*)&sK[kk * LDK + d0] = kv;
    }
    // ---- stage V^T: sVt[d][k], packed u16x2 (k pair) writes ----
    {
      int kp = tid >> 3, d0 = (tid & 7) * 8;
      u16x8 v0 = *(const u16x8*)(vr + hb + (size_t)(k0 + 2 * kp) * 64 + d0);
      u16x8 v1 = *(const u16x8*)(vr + hb + (size_t)(k0 + 2 * kp + 1) * 64 + d0);
      #pragma unroll
      for (int u = 0; u < 8; ++u) {
        u16x2 pk; pk[0] = v0[u]; pk[1] = v1[u];
        *(u16x2*)&sVt[(d0 + u) * LDVT + 2 * kp] = pk;
      }
    }
    __syncthreads();

    if (k0 > qmaxw) continue;        // tile fully masked for this wave (uniform)

    // ---- QK^T (swapped): accs[qf][kt][j] = S[q=l16][k=k0+kt*16+lq*4+j]
    f32x4 accs[2][4] = {};
    #pragma unroll
    for (int kt = 0; kt < 4; ++kt) {
      bf16x8 kf0 = u2b8(*(const u16x8*)&sK[(kt * 16 + l16) * LDK + lq * 8]);
      bf16x8 kf1 = u2b8(*(const u16x8*)&sK[(kt * 16 + l16) * LDK + 32 + lq * 8]);
      accs[0][kt] = __builtin_amdgcn_mfma_f32_16x16x32_bf16(kf0, qv[0][0], accs[0][kt], 0, 0, 0);
      accs[0][kt] = __builtin_amdgcn_mfma_f32_16x16x32_bf16(kf1, qv[0][1], accs[0][kt], 0, 0, 0);
      accs[1][kt] = __builtin_amdgcn_mfma_f32_16x16x32_bf16(kf0, qv[1][0], accs[1][kt], 0, 0, 0);
      accs[1][kt] = __builtin_amdgcn_mfma_f32_16x16x32_bf16(kf1, qv[1][1], accs[1][kt], 0, 0, 0);
    }

    const bool needmask = (k0 + 63) > (qbase + w * 32);   // wave-uniform
    #pragma unroll
    for (int qf = 0; qf < 2; ++qf) {
      const int qrow = qbase + w * 32 + qf * 16 + l16;
      if (needmask) {
        #pragma unroll
        for (int kt = 0; kt < 4; ++kt)
          #pragma unroll
          for (int j = 0; j < 4; ++j)
            if (k0 + kt * 16 + lq * 4 + j > qrow) accs[qf][kt][j] = -1e30f;
      }
      // row max for q=l16: 16 in-lane + 2 shfl (k spread across lq groups)
      float mx = accs[qf][0][0];
      #pragma unroll
      for (int kt = 0; kt < 4; ++kt)
        #pragma unroll
        for (int j = 0; j < 4; ++j) mx = fmaxf(mx, accs[qf][kt][j]);
      mx = fmaxf(mx, __shfl_xor(mx, 16));
      mx = fmaxf(mx, __shfl_xor(mx, 32));

      if (!__all(mx <= mrow[qf])) {      // defer-max: exact skip when no new max
        float mnew = fmaxf(mrow[qf], mx);
        float corr = __builtin_amdgcn_exp2f(mrow[qf] - mnew);   // row q=l16
        lrow[qf] *= corr;
        mrow[qf] = mnew;
        // broadcast corr into D-row space (q=lq*4+j) before scaling O  [R1 fix]
        f32x4 corrv;
        #pragma unroll
        for (int j = 0; j < 4; ++j) corrv[j] = __shfl(corr, lq * 4 + j);
        #pragma unroll
        for (int dt = 0; dt < 4; ++dt) o[qf][dt] *= corrv;
      }
      const float mu = mrow[qf];
      float lsum = 0.0f;
      #pragma unroll
      for (int kt = 0; kt < 4; ++kt) {
        bf16x4 pk;
        #pragma unroll
        for (int j = 0; j < 4; ++j) {
          float p = __builtin_amdgcn_exp2f(accs[qf][kt][j] - mu);
          lsum += p;
          pk[j] = (__bf16)p;
        }
        *(bf16x4*)&sP[w][(qf * 16 + l16) * LDP + kt * 16 + lq * 4] = pk;
      }
      lrow[qf] += lsum;
    }

    // ---- PV: O[q][d] += P[q][k] * V[k][d] (B-frag from sVt = V^T) ----
    #pragma unroll
    for (int kc = 0; kc < 2; ++kc) {
      bf16x8 pa0 = u2b8(*(const u16x8*)&sP[w][(l16) * LDP + kc * 32 + lq * 8]);
      bf16x8 pa1 = u2b8(*(const u16x8*)&sP[w][(16 + l16) * LDP + kc * 32 + lq * 8]);
      #pragma unroll
      for (int dt = 0; dt < 4; ++dt) {
        bf16x8 vt = u2b8(*(const u16x8*)&sVt[(dt * 16 + l16) * LDVT + kc * 32 + lq * 8]);
        o[0][dt] = __builtin_amdgcn_mfma_f32_16x16x32_bf16(pa0, vt, o[0][dt], 0, 0, 0);
        o[1][dt] = __builtin_amdgcn_mfma_f32_16x16x32_bf16(pa1, vt, o[1][dt], 0, 0, 0);
      }
    }
  }

  // finalize: full row denom in l16-space, broadcast 1/l into D-row space.
  const int b = bh >> 4, h = bh & 15;
  #pragma unroll
  for (int qf = 0; qf < 2; ++qf) {
    float l = lrow[qf];
    l += __shfl_xor(l, 16);
    l += __shfl_xor(l, 32);
    float linv = 1.0f / l;
    #pragma unroll
    for (int j = 0; j < 4; ++j) {
      float lj = __shfl(linv, lq * 4 + j);   // lane r (r<16) holds row r's denom
      int row = qbase + w * 32 + qf * 16 + lq * 4 + j;
      u16* orow = ao + ((size_t)(b * T_ + row)) * C_ + h * 64;
      #pragma unroll
      for (int dt = 0; dt < 4; ++dt)
        orow[dt * 16 + l16] = f2b(o[qf][dt][j] * lj);
    }
  }
}

// ------------------------------- launcher ----------------------------------
// ws layout (bytes):                              size
//   xb     @ 0           bf16 x           8,388,608
//   wqkvT  @ 8388608     bf16 w_qkv^T     6,291,456
//   woutT  @ 14680064    bf16 w_out^T     2,097,152
//   qkv    @ 16777216    bf16 qkv        25,165,824
//   qr     @ 41943040    bf16 [B,H,T,D]   8,388,608
//   kr     @ 50331648                     8,388,608
//   vr     @ 58720256                     8,388,608
//   ao     @ 67108864    bf16 attn out    8,388,608
//   cosT   @ 75497472    f32                262,144
//   sinT   @ 75759616    f32                262,144
extern "C" void kernel_launch(void* const* d_in, const int* in_sizes, int n_in,
                              void* d_out, int out_size, void* d_ws, size_t ws_size,
                              hipStream_t stream) {
  const float* x     = (const float*)d_in[0];
  const float* w_qkv = (const float*)d_in[1];
  const float* w_out = (const float*)d_in[2];
  float* out = (float*)d_out;
  char* ws = (char*)d_ws;

  u16* xb     = (u16*)(ws + 0);
  u16* wqkvT  = (u16*)(ws + 8388608);
  u16* woutT  = (u16*)(ws + 14680064);
  u16* qkv    = (u16*)(ws + 16777216);
  u16* qr     = (u16*)(ws + 41943040);
  u16* kr     = (u16*)(ws + 50331648);
  u16* vr     = (u16*)(ws + 58720256);
  u16* ao     = (u16*)(ws + 67108864);
  float* cosT = (float*)(ws + 75497472);
  float* sinT = (float*)(ws + 75759616);

  rope_table_kernel<<<256, 256, 0, stream>>>(cosT, sinT);
  cast_x_kernel<<<4096, 256, 0, stream>>>(x, xb);
  transpose_cast_kernel<<<dim3(96, 32), 256, 0, stream>>>(w_qkv, wqkvT, C_, F_);
  transpose_cast_kernel<<<dim3(32, 32), 256, 0, stream>>>(w_out, woutT, C_, C_);
  gemm_bt_kernel<u16><<<dim3(F_ / 128, M_ / 128), 256, 0, stream>>>(xb, wqkvT, qkv, M_, F_, C_);
  rope_reorg_kernel<<<8192, 256, 0, stream>>>(qkv, cosT, sinT, qr, kr, vr);
  attn_mfma_kernel<<<dim3(B_ * H_, T_ / 128), 256, 0, stream>>>(qr, kr, vr, ao);
  gemm_bt_kernel<float><<<dim3(C_ / 128, M_ / 128), 256, 0, stream>>>(ao, woutT, out, M_, C_, C_);
}

// Round 4
// 155.292 us; speedup vs baseline: 8.0342x; 1.0291x over previous
//
#include <hip/hip_runtime.h>
#include <stdint.h>

// ---------------------------------------------------------------------------
// MultiHeadSelfAttention: x(2,2048,1024) fp32, w_qkv(1024,3072), w_out(1024,1024)
// R3: (a) attn: conflict-free V^T staging (was 8-way: row stride 8*144B ≡ 0
// mod 128B -> bank indep of lane&7), K/V LDS double-buffer with reg-staged
// prefetch (T14) -> 1 barrier/tile, fmax tree. (b) GEMM: global_load_lds(16)
// m97-structure staging (linear [128][32] LDS, wave-uniform dest + lane*16).
// ---------------------------------------------------------------------------

#define B_ 2
#define T_ 2048
#define C_ 1024
#define H_ 16
#define D_ 64
#define F_ 3072
#define M_ 4096

typedef unsigned short u16;
typedef unsigned int u32;
typedef u16 u16x2 __attribute__((ext_vector_type(2)));
typedef u16 u16x4 __attribute__((ext_vector_type(4)));
typedef u16 u16x8 __attribute__((ext_vector_type(8)));
typedef __bf16 bf16x4 __attribute__((ext_vector_type(4)));
typedef __bf16 bf16x8 __attribute__((ext_vector_type(8)));
typedef float f32x4 __attribute__((ext_vector_type(4)));

__device__ __forceinline__ float b2f(u16 u) {
  union { unsigned int i; float f; } v; v.i = ((unsigned int)u) << 16; return v.f;
}
__device__ __forceinline__ u16 f2b(float f) {  // RNE, finite inputs
  unsigned int u = __float_as_uint(f);
  u += 0x7fffu + ((u >> 16) & 1u);
  return (u16)(u >> 16);
}
__device__ __forceinline__ bf16x8 u2b8(u16x8 v) {
  union { u16x8 u; bf16x8 b; } x; x.u = v; return x.b;
}

// --------------------------- small prep kernels ----------------------------

__global__ __launch_bounds__(256) void rope_table_kernel(float* cosT, float* sinT) {
  int idx = blockIdx.x * 256 + threadIdx.x;    // T_*32 = 65536 threads
  int t = idx >> 5, i = idx & 31;
  float inv_freq = powf(10000.0f, -(float)(2 * i) / 64.0f);
  float ang = (float)t * inv_freq;
  cosT[idx] = cosf(ang);
  sinT[idx] = sinf(ang);
}

__global__ __launch_bounds__(256) void cast_x_kernel(const float* __restrict__ x,
                                                     u16* __restrict__ xb) {
  int i = blockIdx.x * 256 + threadIdx.x;      // M_*C_/4 threads
  float4 v = ((const float4*)x)[i];
  u16x4 r;
  r[0] = f2b(v.x); r[1] = f2b(v.y); r[2] = f2b(v.z); r[3] = f2b(v.w);
  ((u16x4*)xb)[i] = r;
}

// out[c][r] = bf16(in[r][c]);  R rows, Ccol cols in input. 32x32 tiles.
__global__ __launch_bounds__(256) void transpose_cast_kernel(const float* __restrict__ in,
                                                             u16* __restrict__ out,
                                                             int R, int Ccol) {
  __shared__ float tile[32][33];
  int c0 = blockIdx.x * 32, r0 = blockIdx.y * 32;
  int tx = threadIdx.x & 31, ty = threadIdx.x >> 5;   // ty = 0..7
  #pragma unroll
  for (int i = 0; i < 32; i += 8)
    tile[ty + i][tx] = in[(size_t)(r0 + ty + i) * Ccol + c0 + tx];
  __syncthreads();
  #pragma unroll
  for (int i = 0; i < 32; i += 8)
    out[(size_t)(c0 + ty + i) * R + r0 + tx] = f2b(tile[tx][ty + i]);
}

// ------------------------------- MFMA GEMM ---------------------------------
// C[M,N] = A[M,K] * Bt[N,K]^T, bf16 in, TO out. 128x128 tile, BK=32, 4 waves,
// 4x4 16x16x32 frags. Staging via global_load_lds width=16 (m97 structure):
// LDS linear [128][32]; dest = wave-uniform base + lane*16B (HW rule).
template <typename TO>
__global__ __launch_bounds__(256) void gemm_bt_kernel(const u16* __restrict__ A,
                                                      const u16* __restrict__ Bt,
                                                      TO* __restrict__ Cm,
                                                      int M, int N, int K) {
  __shared__ u16 sA[128 * 32];
  __shared__ u16 sB[128 * 32];
  const int tid = threadIdx.x;
  const int lane = tid & 63;
  const int wv = tid >> 6;
  const int wr = wv >> 1, wc = wv & 1;
  const int l16 = lane & 15, lq = lane >> 4;
  const int rowBase = blockIdx.y * 128;
  const int colBase = blockIdx.x * 128;

  f32x4 acc[4][4] = {};

  const int e0 = wv * 1024 + lane * 8;      // this lane's elem offset, chunk 0

  for (int k0 = 0; k0 < K; k0 += 32) {
    #pragma unroll
    for (int s = 0; s < 2; ++s) {
      int e = e0 + s * 512;
      int r = e >> 5, c = e & 31;
      __builtin_amdgcn_global_load_lds(
          (const __attribute__((address_space(1))) u32*)(A + (size_t)(rowBase + r) * K + k0 + c),
          (__attribute__((address_space(3))) u32*)&sA[wv * 1024 + s * 512], 16, 0, 0);
      __builtin_amdgcn_global_load_lds(
          (const __attribute__((address_space(1))) u32*)(Bt + (size_t)(colBase + r) * K + k0 + c),
          (__attribute__((address_space(3))) u32*)&sB[wv * 1024 + s * 512], 16, 0, 0);
    }
    __syncthreads();   // drains vmcnt (incl. global_load_lds) per compiler rule
    bf16x8 af[4], bf[4];
    #pragma unroll
    for (int m = 0; m < 4; ++m)
      af[m] = u2b8(*(const u16x8*)&sA[(wr * 64 + m * 16 + l16) * 32 + lq * 8]);
    #pragma unroll
    for (int n = 0; n < 4; ++n)
      bf[n] = u2b8(*(const u16x8*)&sB[(wc * 64 + n * 16 + l16) * 32 + lq * 8]);
    #pragma unroll
    for (int m = 0; m < 4; ++m)
      #pragma unroll
      for (int n = 0; n < 4; ++n)
        acc[m][n] = __builtin_amdgcn_mfma_f32_16x16x32_bf16(af[m], bf[n], acc[m][n], 0, 0, 0);
    __syncthreads();
  }

  // C/D layout (verified m89): col = lane&15, row = (lane>>4)*4 + reg
  #pragma unroll
  for (int m = 0; m < 4; ++m) {
    #pragma unroll
    for (int n = 0; n < 4; ++n) {
      int row = rowBase + wr * 64 + m * 16 + lq * 4;
      int col = colBase + wc * 64 + n * 16 + l16;
      #pragma unroll
      for (int j = 0; j < 4; ++j) {
        float v = acc[m][n][j];
        if constexpr (sizeof(TO) == 2) {
          Cm[(size_t)(row + j) * N + col] = f2b(v);
        } else {
          Cm[(size_t)(row + j) * N + col] = v;
        }
      }
    }
  }
}

// ----------------------------- RoPE + reorg --------------------------------
// qkv[M_,F_] bf16 -> qr/kr/vr [B,H,T,D] bf16 (rope on q,k; copy v)
// qr is PRE-SCALED by 0.125*log2(e) (exp2-domain softmax, single bf16 round).
__global__ __launch_bounds__(256) void rope_reorg_kernel(const u16* __restrict__ qkv,
                                                         const float* __restrict__ cosT,
                                                         const float* __restrict__ sinT,
                                                         u16* __restrict__ qr,
                                                         u16* __restrict__ kr,
                                                         u16* __restrict__ vr) {
  const float QSC = 0.125f * 1.44269504f;
  int idx = blockIdx.x * 256 + threadIdx.x;   // B*T*H*32 = 2^21 threads
  int d2 = idx & 31;
  int h = (idx >> 5) & 15;
  int t = (idx >> 9) & 2047;
  int b = idx >> 20;
  size_t base = (size_t)(b * T_ + t) * F_ + h * 64 + d2 * 2;
  float qe = b2f(qkv[base]),        qo = b2f(qkv[base + 1]);
  float ke = b2f(qkv[base + C_]),   ko = b2f(qkv[base + C_ + 1]);
  float cv = cosT[t * 32 + d2], sv = sinT[t * 32 + d2];
  size_t ob = ((size_t)(b * H_ + h) * T_ + t) * D_ + d2 * 2;
  qr[ob]     = f2b((qe * cv - qo * sv) * QSC);
  qr[ob + 1] = f2b((qe * sv + qo * cv) * QSC);
  kr[ob]     = f2b(ke * cv - ko * sv);
  kr[ob + 1] = f2b(ke * sv + ko * cv);
  vr[ob]     = qkv[base + 2 * C_];
  vr[ob + 1] = qkv[base + 2 * C_ + 1];
}

// ------------------------- MFMA flash attention ----------------------------
// Swapped QK^T; softmax state in q=l16 space, O accumulator in q=lq*4+j space;
// cross-space transfers via __shfl(.., lq*4+j) (R2-verified).
// R3: K/V double-buffered LDS + reg-staged prefetch, 1 barrier/tile.
// V^T staging mapping (kp=tid&31, dblk=tid>>5): write bank = (36u+kp)%32 with
// kp spanning 0..31 per half-wave -> conflict-free (was 8-way).
__global__ __launch_bounds__(256) void attn_mfma_kernel(const u16* __restrict__ qr,
                                                        const u16* __restrict__ kr,
                                                        const u16* __restrict__ vr,
                                                        u16* __restrict__ ao) {
  constexpr int LDK = 72, LDVT = 72, LDP = 72;
  __shared__ u16 sK[2][64 * LDK];
  __shared__ u16 sVt[2][64 * LDVT];              // sVt[buf][d][k]
  __shared__ u16 sP[4][32 * LDP];                // per-wave P[q][k]

  const int tid = threadIdx.x;
  const int lane = tid & 63;
  const int w = tid >> 6;
  const int l16 = lane & 15, lq = lane >> 4;
  const int bh = blockIdx.x;
  const int qt = (int)gridDim.y - 1 - (int)blockIdx.y;   // long blocks first
  const int qbase = qt * 128;
  const size_t hb = (size_t)bh * (T_ * D_);

  // Q frags (pre-scaled bf16, direct reinterpret)
  bf16x8 qv[2][2];
  #pragma unroll
  for (int qf = 0; qf < 2; ++qf)
    #pragma unroll
    for (int dc = 0; dc < 2; ++dc) {
      int row = qbase + w * 32 + qf * 16 + l16;
      qv[qf][dc] = u2b8(*(const u16x8*)(qr + hb + (size_t)row * 64 + dc * 32 + lq * 8));
    }

  f32x4 o[2][4] = {};                 // o[qf][dt]: O[q=lq*4+j][d=dt*16+l16]
  float mrow[2] = {-1e30f, -1e30f};   // running max (log2 domain), row q=l16
  float lrow[2] = {0.0f, 0.0f};       // per-lane partial denom, row q=l16

  // staging index maps
  const int skk = tid >> 3;           // K row 0..31 (and +32)
  const int sd0 = (tid & 7) * 8;      // K col octet
  const int vkp = tid & 31;           // V k-pair 0..31
  const int vdb = tid >> 5;           // V d-block 0..7

  u16x8 rk0, rk1, rv0, rv1;
#define LOADKV(k0)                                                             \
  {                                                                            \
    rk0 = *(const u16x8*)(kr + hb + (size_t)((k0) + skk) * 64 + sd0);          \
    rk1 = *(const u16x8*)(kr + hb + (size_t)((k0) + 32 + skk) * 64 + sd0);     \
    rv0 = *(const u16x8*)(vr + hb + (size_t)((k0) + 2 * vkp) * 64 + vdb * 8);  \
    rv1 = *(const u16x8*)(vr + hb + (size_t)((k0) + 2 * vkp + 1) * 64 + vdb * 8); \
  }
#define WRITEKV(buf)                                                           \
  {                                                                            \
    *(u16x8*)&sK[buf][skk * LDK + sd0] = rk0;                                  \
    *(u16x8*)&sK[buf][(32 + skk) * LDK + sd0] = rk1;                           \
    _Pragma("unroll")                                                          \
    for (int u = 0; u < 8; ++u) {                                              \
      u16x2 pk; pk[0] = rv0[u]; pk[1] = rv1[u];                                \
      *(u16x2*)&sVt[buf][(vdb * 8 + u) * LDVT + 2 * vkp] = pk;                 \
    }                                                                          \
  }

  LOADKV(0);
  WRITEKV(0);
  __syncthreads();

  const int qmaxw = qbase + w * 32 + 31;   // max q-row this wave owns
  const int nt = qt * 2 + 2;
  int cur = 0;
  for (int it = 0; it < nt; ++it) {
    const int k0 = it * 64;
    const bool more = (it + 1 < nt);
    if (more) LOADKV(k0 + 64);           // prefetch next tile into regs

    if (k0 <= qmaxw) {                   // else fully masked for this wave
      // ---- QK^T (swapped): accs[qf][kt][j] = S[q=l16][k=k0+kt*16+lq*4+j]
      f32x4 accs[2][4] = {};
      #pragma unroll
      for (int kt = 0; kt < 4; ++kt) {
        bf16x8 kf0 = u2b8(*(const u16x8*)&sK[cur][(kt * 16 + l16) * LDK + lq * 8]);
        bf16x8 kf1 = u2b8(*(const u16x8*)&sK[cur][(kt * 16 + l16) * LDK + 32 + lq * 8]);
        accs[0][kt] = __builtin_amdgcn_mfma_f32_16x16x32_bf16(kf0, qv[0][0], accs[0][kt], 0, 0, 0);
        accs[0][kt] = __builtin_amdgcn_mfma_f32_16x16x32_bf16(kf1, qv[0][1], accs[0][kt], 0, 0, 0);
        accs[1][kt] = __builtin_amdgcn_mfma_f32_16x16x32_bf16(kf0, qv[1][0], accs[1][kt], 0, 0, 0);
        accs[1][kt] = __builtin_amdgcn_mfma_f32_16x16x32_bf16(kf1, qv[1][1], accs[1][kt], 0, 0, 0);
      }

      const bool needmask = (k0 + 63) > (qbase + w * 32);   // wave-uniform
      #pragma unroll
      for (int qf = 0; qf < 2; ++qf) {
        const int qrow = qbase + w * 32 + qf * 16 + l16;
        if (needmask) {
          #pragma unroll
          for (int kt = 0; kt < 4; ++kt)
            #pragma unroll
            for (int j = 0; j < 4; ++j)
              if (k0 + kt * 16 + lq * 4 + j > qrow) accs[qf][kt][j] = -1e30f;
        }
        // row max for q=l16: depth-4 tree + 2 shfl (k spread across lq groups)
        float m0 = fmaxf(fmaxf(accs[qf][0][0], accs[qf][0][1]), fmaxf(accs[qf][0][2], accs[qf][0][3]));
        float m1 = fmaxf(fmaxf(accs[qf][1][0], accs[qf][1][1]), fmaxf(accs[qf][1][2], accs[qf][1][3]));
        float m2 = fmaxf(fmaxf(accs[qf][2][0], accs[qf][2][1]), fmaxf(accs[qf][2][2], accs[qf][2][3]));
        float m3 = fmaxf(fmaxf(accs[qf][3][0], accs[qf][3][1]), fmaxf(accs[qf][3][2], accs[qf][3][3]));
        float mx = fmaxf(fmaxf(m0, m1), fmaxf(m2, m3));
        mx = fmaxf(mx, __shfl_xor(mx, 16));
        mx = fmaxf(mx, __shfl_xor(mx, 32));

        if (!__all(mx <= mrow[qf])) {    // defer-max: exact skip when no new max
          float mnew = fmaxf(mrow[qf], mx);
          float corr = __builtin_amdgcn_exp2f(mrow[qf] - mnew);   // row q=l16
          lrow[qf] *= corr;
          mrow[qf] = mnew;
          // broadcast corr into D-row space (q=lq*4+j) before scaling O
          f32x4 corrv;
          #pragma unroll
          for (int j = 0; j < 4; ++j) corrv[j] = __shfl(corr, lq * 4 + j);
          #pragma unroll
          for (int dt = 0; dt < 4; ++dt) o[qf][dt] *= corrv;
        }
        const float mu = mrow[qf];
        float ps[4];
        #pragma unroll
        for (int kt = 0; kt < 4; ++kt) {
          bf16x4 pk; float s = 0.0f;
          #pragma unroll
          for (int j = 0; j < 4; ++j) {
            float p = __builtin_amdgcn_exp2f(accs[qf][kt][j] - mu);
            s += p;
            pk[j] = (__bf16)p;
          }
          ps[kt] = s;
          *(bf16x4*)&sP[w][(qf * 16 + l16) * LDP + kt * 16 + lq * 4] = pk;
        }
        lrow[qf] += (ps[0] + ps[1]) + (ps[2] + ps[3]);
      }

      // ---- PV: O[q][d] += P[q][k] * V[k][d] (B-frag from sVt = V^T) ----
      #pragma unroll
      for (int kc = 0; kc < 2; ++kc) {
        bf16x8 pa0 = u2b8(*(const u16x8*)&sP[w][(l16) * LDP + kc * 32 + lq * 8]);
        bf16x8 pa1 = u2b8(*(const u16x8*)&sP[w][(16 + l16) * LDP + kc * 32 + lq * 8]);
        #pragma unroll
        for (int dt = 0; dt < 4; ++dt) {
          bf16x8 vt = u2b8(*(const u16x8*)&sVt[cur][(dt * 16 + l16) * LDVT + kc * 32 + lq * 8]);
          o[0][dt] = __builtin_amdgcn_mfma_f32_16x16x32_bf16(pa0, vt, o[0][dt], 0, 0, 0);
          o[1][dt] = __builtin_amdgcn_mfma_f32_16x16x32_bf16(pa1, vt, o[1][dt], 0, 0, 0);
        }
      }
    }

    if (more) WRITEKV(cur ^ 1);          // write prefetched tile to other buffer
    __syncthreads();                     // one barrier per tile
    cur ^= 1;
  }

  // finalize: full row denom in l16-space, broadcast 1/l into D-row space.
  const int b = bh >> 4, h = bh & 15;
  #pragma unroll
  for (int qf = 0; qf < 2; ++qf) {
    float l = lrow[qf];
    l += __shfl_xor(l, 16);
    l += __shfl_xor(l, 32);
    float linv = 1.0f / l;
    #pragma unroll
    for (int j = 0; j < 4; ++j) {
      float lj = __shfl(linv, lq * 4 + j);   // lane r (r<16) holds row r's denom
      int row = qbase + w * 32 + qf * 16 + lq * 4 + j;
      u16* orow = ao + ((size_t)(b * T_ + row)) * C_ + h * 64;
      #pragma unroll
      for (int dt = 0; dt < 4; ++dt)
        orow[dt * 16 + l16] = f2b(o[qf][dt][j] * lj);
    }
  }
}

// ------------------------------- launcher ----------------------------------
// ws layout (bytes):                              size
//   xb     @ 0           bf16 x           8,388,608
//   wqkvT  @ 8388608     bf16 w_qkv^T     6,291,456
//   woutT  @ 14680064    bf16 w_out^T     2,097,152
//   qkv    @ 16777216    bf16 qkv        25,165,824
//   qr     @ 41943040    bf16 [B,H,T,D]   8,388,608
//   kr     @ 50331648                     8,388,608
//   vr     @ 58720256                     8,388,608
//   ao     @ 67108864    bf16 attn out    8,388,608
//   cosT   @ 75497472    f32                262,144
//   sinT   @ 75759616    f32                262,144
extern "C" void kernel_launch(void* const* d_in, const int* in_sizes, int n_in,
                              void* d_out, int out_size, void* d_ws, size_t ws_size,
                              hipStream_t stream) {
  const float* x     = (const float*)d_in[0];
  const float* w_qkv = (const float*)d_in[1];
  const float* w_out = (const float*)d_in[2];
  float* out = (float*)d_out;
  char* ws = (char*)d_ws;

  u16* xb     = (u16*)(ws + 0);
  u16* wqkvT  = (u16*)(ws + 8388608);
  u16* woutT  = (u16*)(ws + 14680064);
  u16* qkv    = (u16*)(ws + 16777216);
  u16* qr     = (u16*)(ws + 41943040);
  u16* kr     = (u16*)(ws + 50331648);
  u16* vr     = (u16*)(ws + 58720256);
  u16* ao     = (u16*)(ws + 67108864);
  float* cosT = (float*)(ws + 75497472);
  float* sinT = (float*)(ws + 75759616);

  rope_table_kernel<<<256, 256, 0, stream>>>(cosT, sinT);
  cast_x_kernel<<<4096, 256, 0, stream>>>(x, xb);
  transpose_cast_kernel<<<dim3(96, 32), 256, 0, stream>>>(w_qkv, wqkvT, C_, F_);
  transpose_cast_kernel<<<dim3(32, 32), 256, 0, stream>>>(w_out, woutT, C_, C_);
  gemm_bt_kernel<u16><<<dim3(F_ / 128, M_ / 128), 256, 0, stream>>>(xb, wqkvT, qkv, M_, F_, C_);
  rope_reorg_kernel<<<8192, 256, 0, stream>>>(qkv, cosT, sinT, qr, kr, vr);
  attn_mfma_kernel<<<dim3(B_ * H_, T_ / 128), 256, 0, stream>>>(qr, kr, vr, ao);
  gemm_bt_kernel<float><<<dim3(C_ / 128, M_ / 128), 256, 0, stream>>>(ao, woutT, out, M_, C_, C_);
}

// Round 5
// 141.231 us; speedup vs baseline: 8.8340x; 1.0996x over previous
//
#include <hip/hip_runtime.h>
#include <stdint.h>

// ---------------------------------------------------------------------------
// MultiHeadSelfAttention: x(2,2048,1024) fp32, w_qkv(1024,3072), w_out(1024,1024)
// R4 attn rewrite (R3 was latency-bound: occ 12.7%, both pipes idle):
//  - k-slot permutation: stage V rows bit-permuted (vrow = [b5 b2 b4 b3 b1 b0])
//    so the PV A-fragment is the lane's OWN exp2'd QK output registers
//    (concat(pk[2kc],pk[2kc+1])) -> sP LDS round-trip deleted entirely.
//  - 64 q/block (4 waves x 16 rows), grid 32x32=1024 blocks; LDS 36.9KB ->
//    4 blocks/CU (launch_bounds(256,4)) = 16 waves/CU.
//  - setprio(1) around MFMA clusters (T5).
// GEMMs unchanged from R3 (global_load_lds m97-structure).
// ---------------------------------------------------------------------------

#define B_ 2
#define T_ 2048
#define C_ 1024
#define H_ 16
#define D_ 64
#define F_ 3072
#define M_ 4096

typedef unsigned short u16;
typedef unsigned int u32;
typedef u16 u16x2 __attribute__((ext_vector_type(2)));
typedef u16 u16x4 __attribute__((ext_vector_type(4)));
typedef u16 u16x8 __attribute__((ext_vector_type(8)));
typedef __bf16 bf16x4 __attribute__((ext_vector_type(4)));
typedef __bf16 bf16x8 __attribute__((ext_vector_type(8)));
typedef float f32x4 __attribute__((ext_vector_type(4)));

__device__ __forceinline__ float b2f(u16 u) {
  union { unsigned int i; float f; } v; v.i = ((unsigned int)u) << 16; return v.f;
}
__device__ __forceinline__ u16 f2b(float f) {  // RNE, finite inputs
  unsigned int u = __float_as_uint(f);
  u += 0x7fffu + ((u >> 16) & 1u);
  return (u16)(u >> 16);
}
__device__ __forceinline__ bf16x8 u2b8(u16x8 v) {
  union { u16x8 u; bf16x8 b; } x; x.u = v; return x.b;
}

// --------------------------- small prep kernels ----------------------------

__global__ __launch_bounds__(256) void rope_table_kernel(float* cosT, float* sinT) {
  int idx = blockIdx.x * 256 + threadIdx.x;    // T_*32 = 65536 threads
  int t = idx >> 5, i = idx & 31;
  float inv_freq = powf(10000.0f, -(float)(2 * i) / 64.0f);
  float ang = (float)t * inv_freq;
  cosT[idx] = cosf(ang);
  sinT[idx] = sinf(ang);
}

__global__ __launch_bounds__(256) void cast_x_kernel(const float* __restrict__ x,
                                                     u16* __restrict__ xb) {
  int i = blockIdx.x * 256 + threadIdx.x;      // M_*C_/4 threads
  float4 v = ((const float4*)x)[i];
  u16x4 r;
  r[0] = f2b(v.x); r[1] = f2b(v.y); r[2] = f2b(v.z); r[3] = f2b(v.w);
  ((u16x4*)xb)[i] = r;
}

// out[c][r] = bf16(in[r][c]);  R rows, Ccol cols in input. 32x32 tiles.
__global__ __launch_bounds__(256) void transpose_cast_kernel(const float* __restrict__ in,
                                                             u16* __restrict__ out,
                                                             int R, int Ccol) {
  __shared__ float tile[32][33];
  int c0 = blockIdx.x * 32, r0 = blockIdx.y * 32;
  int tx = threadIdx.x & 31, ty = threadIdx.x >> 5;   // ty = 0..7
  #pragma unroll
  for (int i = 0; i < 32; i += 8)
    tile[ty + i][tx] = in[(size_t)(r0 + ty + i) * Ccol + c0 + tx];
  __syncthreads();
  #pragma unroll
  for (int i = 0; i < 32; i += 8)
    out[(size_t)(c0 + ty + i) * R + r0 + tx] = f2b(tile[tx][ty + i]);
}

// ------------------------------- MFMA GEMM ---------------------------------
// C[M,N] = A[M,K] * Bt[N,K]^T, bf16 in, TO out. 128x128 tile, BK=32, 4 waves,
// 4x4 16x16x32 frags. Staging via global_load_lds width=16 (m97 structure).
template <typename TO>
__global__ __launch_bounds__(256) void gemm_bt_kernel(const u16* __restrict__ A,
                                                      const u16* __restrict__ Bt,
                                                      TO* __restrict__ Cm,
                                                      int M, int N, int K) {
  __shared__ u16 sA[128 * 32];
  __shared__ u16 sB[128 * 32];
  const int tid = threadIdx.x;
  const int lane = tid & 63;
  const int wv = tid >> 6;
  const int wr = wv >> 1, wc = wv & 1;
  const int l16 = lane & 15, lq = lane >> 4;
  const int rowBase = blockIdx.y * 128;
  const int colBase = blockIdx.x * 128;

  f32x4 acc[4][4] = {};

  const int e0 = wv * 1024 + lane * 8;      // this lane's elem offset, chunk 0

  for (int k0 = 0; k0 < K; k0 += 32) {
    #pragma unroll
    for (int s = 0; s < 2; ++s) {
      int e = e0 + s * 512;
      int r = e >> 5, c = e & 31;
      __builtin_amdgcn_global_load_lds(
          (const __attribute__((address_space(1))) u32*)(A + (size_t)(rowBase + r) * K + k0 + c),
          (__attribute__((address_space(3))) u32*)&sA[wv * 1024 + s * 512], 16, 0, 0);
      __builtin_amdgcn_global_load_lds(
          (const __attribute__((address_space(1))) u32*)(Bt + (size_t)(colBase + r) * K + k0 + c),
          (__attribute__((address_space(3))) u32*)&sB[wv * 1024 + s * 512], 16, 0, 0);
    }
    __syncthreads();   // drains vmcnt (incl. global_load_lds) per compiler rule
    bf16x8 af[4], bf[4];
    #pragma unroll
    for (int m = 0; m < 4; ++m)
      af[m] = u2b8(*(const u16x8*)&sA[(wr * 64 + m * 16 + l16) * 32 + lq * 8]);
    #pragma unroll
    for (int n = 0; n < 4; ++n)
      bf[n] = u2b8(*(const u16x8*)&sB[(wc * 64 + n * 16 + l16) * 32 + lq * 8]);
    #pragma unroll
    for (int m = 0; m < 4; ++m)
      #pragma unroll
      for (int n = 0; n < 4; ++n)
        acc[m][n] = __builtin_amdgcn_mfma_f32_16x16x32_bf16(af[m], bf[n], acc[m][n], 0, 0, 0);
    __syncthreads();
  }

  // C/D layout (verified m89): col = lane&15, row = (lane>>4)*4 + reg
  #pragma unroll
  for (int m = 0; m < 4; ++m) {
    #pragma unroll
    for (int n = 0; n < 4; ++n) {
      int row = rowBase + wr * 64 + m * 16 + lq * 4;
      int col = colBase + wc * 64 + n * 16 + l16;
      #pragma unroll
      for (int j = 0; j < 4; ++j) {
        float v = acc[m][n][j];
        if constexpr (sizeof(TO) == 2) {
          Cm[(size_t)(row + j) * N + col] = f2b(v);
        } else {
          Cm[(size_t)(row + j) * N + col] = v;
        }
      }
    }
  }
}

// ----------------------------- RoPE + reorg --------------------------------
// qkv[M_,F_] bf16 -> qr/kr/vr [B,H,T,D] bf16 (rope on q,k; copy v)
// qr is PRE-SCALED by 0.125*log2(e) (exp2-domain softmax, single bf16 round).
__global__ __launch_bounds__(256) void rope_reorg_kernel(const u16* __restrict__ qkv,
                                                         const float* __restrict__ cosT,
                                                         const float* __restrict__ sinT,
                                                         u16* __restrict__ qr,
                                                         u16* __restrict__ kr,
                                                         u16* __restrict__ vr) {
  const float QSC = 0.125f * 1.44269504f;
  int idx = blockIdx.x * 256 + threadIdx.x;   // B*T*H*32 = 2^21 threads
  int d2 = idx & 31;
  int h = (idx >> 5) & 15;
  int t = (idx >> 9) & 2047;
  int b = idx >> 20;
  size_t base = (size_t)(b * T_ + t) * F_ + h * 64 + d2 * 2;
  float qe = b2f(qkv[base]),        qo = b2f(qkv[base + 1]);
  float ke = b2f(qkv[base + C_]),   ko = b2f(qkv[base + C_ + 1]);
  float cv = cosT[t * 32 + d2], sv = sinT[t * 32 + d2];
  size_t ob = ((size_t)(b * H_ + h) * T_ + t) * D_ + d2 * 2;
  qr[ob]     = f2b((qe * cv - qo * sv) * QSC);
  qr[ob + 1] = f2b((qe * sv + qo * cv) * QSC);
  kr[ob]     = f2b(ke * cv - ko * sv);
  kr[ob + 1] = f2b(ke * sv + ko * cv);
  vr[ob]     = qkv[base + 2 * C_];
  vr[ob + 1] = qkv[base + 2 * C_ + 1];
}

// ------------------------- MFMA flash attention ----------------------------
// Swapped QK^T; softmax state in q=l16 space, O accumulator in q=lq*4+j space;
// cross-space transfers via __shfl(.., lq*4+j) (R2-verified).
// R4: in-register P via k-slot permutation. PV is sum-over-k, so permuting
// k-slots is legal iff P-slots and V-rows share the permutation. QK D-layout
// owns slots {kt*16+lq*4+j}; PV A-frag needs {kc*32+lq*8+u}. Staging V row
// vrow(r)=[b5 b2 b4 b3 b1 b0] (bit perm of slot r) makes PV A-operand =
// concat(pk[2kc],pk[2kc+1]) = own registers. K stays identity (mask unchanged).
__global__ __launch_bounds__(256, 4) void attn_mfma_kernel(const u16* __restrict__ qr,
                                                           const u16* __restrict__ kr,
                                                           const u16* __restrict__ vr,
                                                           u16* __restrict__ ao) {
  constexpr int LDK = 72, LDVT = 72;
  __shared__ u16 sK[2][64 * LDK];
  __shared__ u16 sVt[2][64 * LDVT];              // sVt[buf][d][k-slot]

  const int tid = threadIdx.x;
  const int lane = tid & 63;
  const int w = tid >> 6;
  const int l16 = lane & 15, lq = lane >> 4;
  const int bh = blockIdx.x;
  const int qt = (int)gridDim.y - 1 - (int)blockIdx.y;   // long blocks first
  const int qbase = qt * 64;
  const size_t hb = (size_t)bh * (T_ * D_);

  // Q frags (pre-scaled bf16): rows qbase + w*16 + l16
  bf16x8 qv[2];
  #pragma unroll
  for (int dc = 0; dc < 2; ++dc) {
    int row = qbase + w * 16 + l16;
    qv[dc] = u2b8(*(const u16x8*)(qr + hb + (size_t)row * 64 + dc * 32 + lq * 8));
  }

  f32x4 o[4] = {};              // o[dt]: O[q=lq*4+j][d=dt*16+l16]
  float mrow = -1e30f;          // running max (log2 domain), row q=l16
  float lrow = 0.0f;            // per-lane partial denom, row q=l16

  // staging index maps
  const int skk = tid >> 3;           // K row 0..31 (and +32)
  const int sd0 = (tid & 7) * 8;      // K col octet
  const int vkp = tid & 31;           // V slot-pair 0..31 (slots 2vkp, 2vkp+1)
  const int vdb = tid >> 5;           // V d-block 0..7
  // true V row for slot r=2*vkp: vrow(r)=32*b5+16*b2+8*b4+4*b3+2*b1+b0 (r bits)
  const int vtr = ((vkp >> 4) & 1) * 32 + ((vkp >> 1) & 1) * 16 +
                  ((vkp >> 3) & 1) * 8 + ((vkp >> 2) & 1) * 4 + (vkp & 1) * 2;

  u16x8 rk0, rk1, rv0, rv1;
#define LOADKV(k0)                                                             \
  {                                                                            \
    rk0 = *(const u16x8*)(kr + hb + (size_t)((k0) + skk) * 64 + sd0);          \
    rk1 = *(const u16x8*)(kr + hb + (size_t)((k0) + 32 + skk) * 64 + sd0);     \
    rv0 = *(const u16x8*)(vr + hb + (size_t)((k0) + vtr) * 64 + vdb * 8);      \
    rv1 = *(const u16x8*)(vr + hb + (size_t)((k0) + vtr + 1) * 64 + vdb * 8);  \
  }
#define WRITEKV(buf)                                                           \
  {                                                                            \
    *(u16x8*)&sK[buf][skk * LDK + sd0] = rk0;                                  \
    *(u16x8*)&sK[buf][(32 + skk) * LDK + sd0] = rk1;                           \
    _Pragma("unroll")                                                          \
    for (int u = 0; u < 8; ++u) {                                              \
      u16x2 pk; pk[0] = rv0[u]; pk[1] = rv1[u];                                \
      *(u16x2*)&sVt[buf][(vdb * 8 + u) * LDVT + 2 * vkp] = pk;                 \
    }                                                                          \
  }

  LOADKV(0);
  WRITEKV(0);
  __syncthreads();

  const int nt = qt + 1;
  int cur = 0;
  for (int it = 0; it < nt; ++it) {
    const int k0 = it * 64;
    const bool more = (it + 1 < nt);
    if (more) LOADKV(k0 + 64);           // prefetch next tile into regs (T14)

    // ---- QK^T (swapped): accs[kt][j] = S[q=l16][slot k0+kt*16+lq*4+j]
    f32x4 accs[4] = {};
    __builtin_amdgcn_s_setprio(1);
    #pragma unroll
    for (int kt = 0; kt < 4; ++kt) {
      bf16x8 kf0 = u2b8(*(const u16x8*)&sK[cur][(kt * 16 + l16) * LDK + lq * 8]);
      bf16x8 kf1 = u2b8(*(const u16x8*)&sK[cur][(kt * 16 + l16) * LDK + 32 + lq * 8]);
      accs[kt] = __builtin_amdgcn_mfma_f32_16x16x32_bf16(kf0, qv[0], accs[kt], 0, 0, 0);
      accs[kt] = __builtin_amdgcn_mfma_f32_16x16x32_bf16(kf1, qv[1], accs[kt], 0, 0, 0);
    }
    __builtin_amdgcn_s_setprio(0);

    const int qrow = qbase + w * 16 + l16;
    if (k0 + 63 > qbase + w * 16) {      // wave-uniform: last tile only
      #pragma unroll
      for (int kt = 0; kt < 4; ++kt)
        #pragma unroll
        for (int j = 0; j < 4; ++j)
          if (k0 + kt * 16 + lq * 4 + j > qrow) accs[kt][j] = -1e30f;
    }
    // row max for q=l16: depth-4 tree + 2 shfl (k spread across lq groups)
    float m0 = fmaxf(fmaxf(accs[0][0], accs[0][1]), fmaxf(accs[0][2], accs[0][3]));
    float m1 = fmaxf(fmaxf(accs[1][0], accs[1][1]), fmaxf(accs[1][2], accs[1][3]));
    float m2 = fmaxf(fmaxf(accs[2][0], accs[2][1]), fmaxf(accs[2][2], accs[2][3]));
    float m3 = fmaxf(fmaxf(accs[3][0], accs[3][1]), fmaxf(accs[3][2], accs[3][3]));
    float mx = fmaxf(fmaxf(m0, m1), fmaxf(m2, m3));
    mx = fmaxf(mx, __shfl_xor(mx, 16));
    mx = fmaxf(mx, __shfl_xor(mx, 32));

    if (!__all(mx <= mrow)) {            // defer-max: exact skip when no new max
      float mnew = fmaxf(mrow, mx);
      float corr = __builtin_amdgcn_exp2f(mrow - mnew);   // row q=l16
      lrow *= corr;
      mrow = mnew;
      // broadcast corr into D-row space (q=lq*4+j) before scaling O
      f32x4 corrv;
      #pragma unroll
      for (int j = 0; j < 4; ++j) corrv[j] = __shfl(corr, lq * 4 + j);
      #pragma unroll
      for (int dt = 0; dt < 4; ++dt) o[dt] *= corrv;
    }
    const float mu = mrow;
    // exp2 + pack: pb[kc][u] : u<4 <- pk[2kc][j=u], u>=4 <- pk[2kc+1][j=u-4]
    u16x8 pb[2];
    float lsum = 0.0f;
    #pragma unroll
    for (int kt = 0; kt < 4; ++kt) {
      #pragma unroll
      for (int j = 0; j < 4; ++j) {
        float p = __builtin_amdgcn_exp2f(accs[kt][j] - mu);
        lsum += p;
        pb[kt >> 1][(kt & 1) * 4 + j] = f2b(p);
      }
    }
    lrow += lsum;

    // ---- PV: A-operand = own registers (slot perm); B from sVt ----
    __builtin_amdgcn_s_setprio(1);
    #pragma unroll
    for (int kc = 0; kc < 2; ++kc) {
      bf16x8 pa = u2b8(pb[kc]);
      #pragma unroll
      for (int dt = 0; dt < 4; ++dt) {
        bf16x8 vt = u2b8(*(const u16x8*)&sVt[cur][(dt * 16 + l16) * LDVT + kc * 32 + lq * 8]);
        o[dt] = __builtin_amdgcn_mfma_f32_16x16x32_bf16(pa, vt, o[dt], 0, 0, 0);
      }
    }
    __builtin_amdgcn_s_setprio(0);

    if (more) WRITEKV(cur ^ 1);          // write prefetched tile to other buffer
    __syncthreads();                     // one barrier per tile
    cur ^= 1;
  }

  // finalize: full row denom in l16-space, broadcast 1/l into D-row space.
  const int b = bh >> 4, h = bh & 15;
  float l = lrow;
  l += __shfl_xor(l, 16);
  l += __shfl_xor(l, 32);
  float linv = 1.0f / l;
  #pragma unroll
  for (int j = 0; j < 4; ++j) {
    float lj = __shfl(linv, lq * 4 + j);   // lane r (r<16) holds row r's denom
    int row = qbase + w * 16 + lq * 4 + j;
    u16* orow = ao + ((size_t)(b * T_ + row)) * C_ + h * 64;
    #pragma unroll
    for (int dt = 0; dt < 4; ++dt)
      orow[dt * 16 + l16] = f2b(o[dt][j] * lj);
  }
}

// ------------------------------- launcher ----------------------------------
// ws layout (bytes):                              size
//   xb     @ 0           bf16 x           8,388,608
//   wqkvT  @ 8388608     bf16 w_qkv^T     6,291,456
//   woutT  @ 14680064    bf16 w_out^T     2,097,152
//   qkv    @ 16777216    bf16 qkv        25,165,824
//   qr     @ 41943040    bf16 [B,H,T,D]   8,388,608
//   kr     @ 50331648                     8,388,608
//   vr     @ 58720256                     8,388,608
//   ao     @ 67108864    bf16 attn out    8,388,608
//   cosT   @ 75497472    f32                262,144
//   sinT   @ 75759616    f32                262,144
extern "C" void kernel_launch(void* const* d_in, const int* in_sizes, int n_in,
                              void* d_out, int out_size, void* d_ws, size_t ws_size,
                              hipStream_t stream) {
  const float* x     = (const float*)d_in[0];
  const float* w_qkv = (const float*)d_in[1];
  const float* w_out = (const float*)d_in[2];
  float* out = (float*)d_out;
  char* ws = (char*)d_ws;

  u16* xb     = (u16*)(ws + 0);
  u16* wqkvT  = (u16*)(ws + 8388608);
  u16* woutT  = (u16*)(ws + 14680064);
  u16* qkv    = (u16*)(ws + 16777216);
  u16* qr     = (u16*)(ws + 41943040);
  u16* kr     = (u16*)(ws + 50331648);
  u16* vr     = (u16*)(ws + 58720256);
  u16* ao     = (u16*)(ws + 67108864);
  float* cosT = (float*)(ws + 75497472);
  float* sinT = (float*)(ws + 75759616);

  rope_table_kernel<<<256, 256, 0, stream>>>(cosT, sinT);
  cast_x_kernel<<<4096, 256, 0, stream>>>(x, xb);
  transpose_cast_kernel<<<dim3(96, 32), 256, 0, stream>>>(w_qkv, wqkvT, C_, F_);
  transpose_cast_kernel<<<dim3(32, 32), 256, 0, stream>>>(w_out, woutT, C_, C_);
  gemm_bt_kernel<u16><<<dim3(F_ / 128, M_ / 128), 256, 0, stream>>>(xb, wqkvT, qkv, M_, F_, C_);
  rope_reorg_kernel<<<8192, 256, 0, stream>>>(qkv, cosT, sinT, qr, kr, vr);
  attn_mfma_kernel<<<dim3(B_ * H_, T_ / 64), 256, 0, stream>>>(qr, kr, vr, ao);
  gemm_bt_kernel<float><<<dim3(C_ / 128, M_ / 128), 256, 0, stream>>>(ao, woutT, out, M_, C_, C_);
}